// Round 13
// baseline (483.680 us; speedup 1.0000x reference)
//
#include <hip/hip_runtime.h>
#include <hip/hip_fp16.h>
#include <hip/hip_cooperative_groups.h>
#include <math.h>

namespace cg = cooperative_groups;

#define NNODES 50000
#define NEDGES 800000
#define NBUCK 256
#define EPB 8192
#define NBLK1 98                    // edge chunks (800000/8192 rounded up)
#define SCANL (NBUCK * NBLK1)       // 25088
#define NPART 49                    // 25088 / 512
#define FCAP 4096                   // per-bucket LDS sort capacity (mean 3125, 17 sigma)
#define NGEMM1 782                  // ceil(50000/64)
#define NPAIR 25000                 // node pairs for agg
#define ARENA 37376                 // LDS arena bytes

typedef _Float16 f16;
typedef _Float16 f16x4 __attribute__((ext_vector_type(4)));
typedef _Float16 f16x8 __attribute__((ext_vector_type(8)));
typedef float    f32x4 __attribute__((ext_vector_type(4)));

// ---------------- helpers ----------------

// redundant exclusive scan of NPART(<=64) partials into LDS sp
__device__ __forceinline__ void scan_partials49(const int* __restrict__ part, int* sp) {
    int t = threadIdx.x;
    if (t < 64) {
        int v = (t < NPART) ? part[t] : 0;
        int incl = v;
        #pragma unroll
        for (int off = 1; off < 64; off <<= 1) {
            int u = __shfl_up(incl, off, 64);
            if (t >= off) incl += u;
        }
        if (t < NPART) sp[t] = incl - v;
    }
    __syncthreads();
}

// ---------------- MFMA GEMM tile (16x16x32 f16, fp32 accum), 512-thr block ----------------
// Xs [64][K] fp16 XOR-swizzled ((row&7)<<4 byte); Ws = W^T [64][K] same swizzle.
// Waves 0-3 compute (wave w -> rows w*16..+16, 4 col-tiles of 16).

template<int K, int XH, int WH>   // XH: X fp16; WH: W preswizzled fp16
__device__ void gemm_tile(char* lds, int bid,
                          const void* __restrict__ Xv, const void* __restrict__ Wsrc,
                          const float* __restrict__ a_src, const float* __restrict__ a_dst,
                          __half* __restrict__ H, float* __restrict__ AS, float* __restrict__ AD)
{
    __half* Xs_h = (__half*)lds;
    __half* Ws_h = (__half*)(lds + (size_t)64 * K * 2);
    constexpr int KF = K / 4;
    constexpr int KFS = (K == 128) ? 5 : 4;
    int t = threadIdx.x;
    int n0 = bid * 64;

    if (WH) {
        const uint2* wsrc = (const uint2*)Wsrc;
        uint2* wdst = (uint2*)Ws_h;
        for (int f = t; f < K * 16; f += 512) wdst[f] = wsrc[f];
    } else {
        const float4* w4 = (const float4*)Wsrc;   // W [K][64] fp32
        for (int idx4 = t; idx4 < K * 16; idx4 += 512) {
            float4 wv = w4[idx4];
            int k = idx4 >> 4;
            int c0 = (idx4 & 15) * 4;
            Ws_h[(c0 + 0) * K + (k ^ (((c0 + 0) & 7) << 3))] = (f16)wv.x;
            Ws_h[(c0 + 1) * K + (k ^ (((c0 + 1) & 7) << 3))] = (f16)wv.y;
            Ws_h[(c0 + 2) * K + (k ^ (((c0 + 2) & 7) << 3))] = (f16)wv.z;
            Ws_h[(c0 + 3) * K + (k ^ (((c0 + 3) & 7) << 3))] = (f16)wv.w;
        }
    }
    for (int f = t; f < 64 * KF; f += 512) {
        int r = f >> KFS, k4 = f & (KF - 1);
        f16x4 hv = {0, 0, 0, 0};
        if (n0 + r < NNODES) {
            if (XH) {
                union { uint2 u; f16x4 h4; } c;
                c.u = ((const uint2*)Xv)[(size_t)(n0 + r) * KF + k4];
                hv = c.h4;
            } else {
                float4 v = ((const float4*)Xv)[(size_t)(n0 + r) * KF + k4];
                hv[0] = (f16)v.x; hv[1] = (f16)v.y; hv[2] = (f16)v.z; hv[3] = (f16)v.w;
            }
        }
        int bo = (k4 * 8) ^ ((r & 7) << 4);
        *(f16x4*)((char*)Xs_h + r * (K * 2) + bo) = hv;
    }
    __syncthreads();

    if (t < 256) {
        int w = t >> 6, l = t & 63;
        int lg = l >> 4, l15 = l & 15;
        int rA = w * 16 + l15;
        int sw = (l15 & 7) << 4;

        f32x4 acc[4];
        #pragma unroll
        for (int ct = 0; ct < 4; ++ct) acc[ct] = (f32x4){0.f, 0.f, 0.f, 0.f};

        const char* pA = (const char*)Xs_h + rA * (K * 2);
        #pragma unroll
        for (int ks = 0; ks < K / 32; ++ks) {
            int ko = ks * 64 + (lg << 4);
            f16x8 a = *(const f16x8*)(pA + (ko ^ sw));
            #pragma unroll
            for (int ct = 0; ct < 4; ++ct) {
                const char* pB = (const char*)Ws_h + (ct * 16 + l15) * (K * 2) + (ko ^ sw);
                f16x8 bfr = *(const f16x8*)pB;
                acc[ct] = __builtin_amdgcn_mfma_f32_16x16x32_f16(a, bfr, acc[ct], 0, 0, 0);
            }
        }

        float asv[4], adv[4];
        #pragma unroll
        for (int ct = 0; ct < 4; ++ct) {
            asv[ct] = a_src[ct * 16 + l15];
            adv[ct] = a_dst[ct * 16 + l15];
        }
        #pragma unroll
        for (int reg = 0; reg < 4; ++reg) {
            int row = n0 + w * 16 + lg * 4 + reg;
            if (row < NNODES) {
                float s1 = 0.f, s2 = 0.f;
                #pragma unroll
                for (int ct = 0; ct < 4; ++ct) {
                    s1 = fmaf(acc[ct][reg], asv[ct], s1);
                    s2 = fmaf(acc[ct][reg], adv[ct], s2);
                }
                #pragma unroll
                for (int o = 1; o < 16; o <<= 1) {
                    s1 += __shfl_xor(s1, o, 64);
                    s2 += __shfl_xor(s2, o, 64);
                }
                #pragma unroll
                for (int ct = 0; ct < 4; ++ct)
                    H[(size_t)row * 64 + ct * 16 + l15] = __float2half(acc[ct][reg]);
                if (l15 == 0) { AS[row] = s1; AD[row] = s2; }
            }
        }
    }
    __syncthreads();
}

// ---------------- per-pair aggregation (R11 layout: 2 nodes/wave) ----------------

template<int RELU, int NORM, int OUTH>
__device__ __forceinline__ void agg_pair(
    int p, int lane, int2* smw,
    const int* __restrict__ esrc, const int* __restrict__ offs,
    const __half* __restrict__ H, const float* __restrict__ AS,
    const float* __restrict__ AD, const float* __restrict__ bias,
    void* __restrict__ outv)
{
    int n0 = 2 * p;
    int half = lane >> 5, fp = lane & 31;
    int nh = n0 + half;                     // always < NNODES (NNODES even)
    int beg = offs[nh], end = offs[nh + 1];
    int deg = end - beg;
    int degO = __shfl_xor(deg, 32, 64);
    int dm = max(deg, degO);
    float2 bp = ((const float2*)bias)[fp];

    if (dm <= 32) {
        float add = AD[nh];
        int s = 0;
        float logit = -3.0e38f;
        if (fp < deg) {
            s = esrc[beg + fp];
            float l0 = AS[s] + add;
            logit = (l0 > 0.f) ? l0 : 0.2f * l0;
        }
        float m = logit;
        #pragma unroll
        for (int o = 16; o > 0; o >>= 1) m = fmaxf(m, __shfl_xor(m, o, 64));
        float wg = (fp < deg) ? __expf(logit - m) : 0.f;
        float z = wg;
        #pragma unroll
        for (int o = 16; o > 0; o >>= 1) z += __shfl_xor(z, o, 64);
        smw[lane] = make_int2(s, __float_as_int(wg));

        const __half2* H2 = (const __half2*)H;
        float2 a0 = {0.f, 0.f}, a1 = {0.f, 0.f};
        int base = half * 32;
        int k = 0;
        for (; k + 1 < dm; k += 2) {
            int4 v = *(const int4*)&smw[base + k];
            float2 h0 = __half22float2(H2[(size_t)v.x * 32 + fp]);
            float2 h1 = __half22float2(H2[(size_t)v.z * 32 + fp]);
            float w0 = __int_as_float(v.y), w1 = __int_as_float(v.w);
            a0.x = fmaf(w0, h0.x, a0.x); a0.y = fmaf(w0, h0.y, a0.y);
            a1.x = fmaf(w1, h1.x, a1.x); a1.y = fmaf(w1, h1.y, a1.y);
        }
        if (k < dm) {
            int2 v = smw[base + k];
            float2 h0 = __half22float2(H2[(size_t)v.x * 32 + fp]);
            float w0 = __int_as_float(v.y);
            a0.x = fmaf(w0, h0.x, a0.x); a0.y = fmaf(w0, h0.y, a0.y);
        }
        float2 acc = {a0.x + a1.x, a0.y + a1.y};
        float rz = (deg > 0) ? (1.0f / z) : 0.f;
        float2 val2 = make_float2(fmaf(acc.x, rz, bp.x), fmaf(acc.y, rz, bp.y));
        if (RELU) { val2.x = fmaxf(val2.x, 0.f); val2.y = fmaxf(val2.y, 0.f); }
        if (NORM) {
            float ss = val2.x * val2.x + val2.y * val2.y;
            #pragma unroll
            for (int o = 16; o > 0; o >>= 1) ss += __shfl_xor(ss, o, 64);
            float inv = 1.0f / fmaxf(sqrtf(ss), 1e-12f);
            val2.x *= inv; val2.y *= inv;
        }
        if (OUTH) ((__half2*)outv)[(size_t)nh * 32 + fp] = __floats2half2_rn(val2.x, val2.y);
        else      ((float2*)outv)[(size_t)nh * 32 + fp] = val2;
        return;
    }

    // rare fallback: per node with the full wave
    #pragma unroll 1
    for (int side = 0; side < 2; ++side) {
        int n = n0 + side;
        int b2 = offs[n], e2 = offs[n + 1];
        int dg = e2 - b2;
        float add = AD[n];
        if (dg <= 64) {
            int s = 0;
            float logit = -3.0e38f;
            if (lane < dg) {
                s = esrc[b2 + lane];
                float l0 = AS[s] + add;
                logit = (l0 > 0.f) ? l0 : 0.2f * l0;
            }
            float m = logit;
            #pragma unroll
            for (int o = 32; o > 0; o >>= 1) m = fmaxf(m, __shfl_xor(m, o, 64));
            float wg = (lane < dg) ? __expf(logit - m) : 0.f;
            float z = wg;
            #pragma unroll
            for (int o = 32; o > 0; o >>= 1) z += __shfl_xor(z, o, 64);
            smw[lane] = make_int2(s, __float_as_int(wg));
            const __half2* H2 = (const __half2*)H;
            float2 a0 = {0.f, 0.f};
            for (int k = half; k < dg; k += 2) {
                int2 v = smw[k];
                float2 h0 = __half22float2(H2[(size_t)v.x * 32 + fp]);
                float w0 = __int_as_float(v.y);
                a0.x = fmaf(w0, h0.x, a0.x); a0.y = fmaf(w0, h0.y, a0.y);
            }
            a0.x += __shfl_xor(a0.x, 32, 64);
            a0.y += __shfl_xor(a0.y, 32, 64);
            float rz = (dg > 0) ? (1.0f / z) : 0.f;
            float2 val2 = make_float2(fmaf(a0.x, rz, bp.x), fmaf(a0.y, rz, bp.y));
            if (RELU) { val2.x = fmaxf(val2.x, 0.f); val2.y = fmaxf(val2.y, 0.f); }
            if (NORM) {
                float ss = val2.x * val2.x + val2.y * val2.y;
                #pragma unroll
                for (int o = 16; o > 0; o >>= 1) ss += __shfl_xor(ss, o, 64);
                float inv = 1.0f / fmaxf(sqrtf(ss), 1e-12f);
                val2.x *= inv; val2.y *= inv;
            }
            if (half == 0) {
                if (OUTH) ((__half2*)outv)[(size_t)n * 32 + fp] = __floats2half2_rn(val2.x, val2.y);
                else      ((float2*)outv)[(size_t)n * 32 + fp] = val2;
            }
        } else {
            float m = -3.0e38f, z = 0.f, acc = 0.f;
            for (int i = b2; i < e2; ++i) {
                int s = esrc[i];
                float l0 = AS[s] + add;
                l0 = (l0 > 0.f) ? l0 : 0.2f * l0;
                float mn = fmaxf(m, l0);
                float sc = __expf(m - mn);
                float wgt = __expf(l0 - mn);
                z = z * sc + wgt;
                acc = acc * sc + wgt * __half2float(H[(size_t)s * 64 + lane]);
                m = mn;
            }
            float val = acc / z + bias[lane];
            if (RELU) val = fmaxf(val, 0.f);
            if (NORM) {
                float ss = val * val;
                #pragma unroll
                for (int o = 32; o > 0; o >>= 1) ss += __shfl_xor(ss, o, 64);
                val = val / fmaxf(sqrtf(ss), 1e-12f);
            }
            if (OUTH) ((__half*)outv)[(size_t)n * 64 + lane] = __float2half(val);
            else      ((float*)outv)[(size_t)n * 64 + lane] = val;
        }
    }
}

// ---------------- the cooperative mega-kernel ----------------

__global__ __launch_bounds__(512, 8) void k_mega(
    const float* __restrict__ x, const int* __restrict__ ei,
    const float* __restrict__ W1, const float* __restrict__ as1,
    const float* __restrict__ ad1, const float* __restrict__ b1,
    const float* __restrict__ W2, const float* __restrict__ as2,
    const float* __restrict__ ad2, const float* __restrict__ b2,
    float* __restrict__ outF,
    __half* __restrict__ H, __half* __restrict__ OUT1,
    float* __restrict__ AS, float* __restrict__ AD,
    int* __restrict__ offs, int* __restrict__ ep, int* __restrict__ esrc,
    int* __restrict__ bcnt, int* __restrict__ boffs, int* __restrict__ part,
    __half* __restrict__ Wt2)
{
    __shared__ __align__(16) char lds[ARENA];
    cg::grid_group grid = cg::this_grid();
    const int* src = ei;
    const int* dst = ei + NEDGES;
    int t = threadIdx.x;

    // ---- P1: gemm1 tiles || bcount chunks || Wt2 prep (all independent) ----
    for (int it = blockIdx.x; it < NGEMM1 + NBLK1 + 1; it += gridDim.x) {
        if (it < NGEMM1) {
            gemm_tile<128, 0, 0>(lds, it, x, W1, as1, ad1, H, AS, AD);
        } else if (it < NGEMM1 + NBLK1) {
            int b = it - NGEMM1;
            int* h = (int*)lds;
            if (t < NBUCK) h[t] = 0;
            __syncthreads();
            const int4* d4 = (const int4*)dst;
            int beg = b * (EPB / 4), end = min(beg + EPB / 4, NEDGES / 4);
            for (int e = beg + t; e < end; e += 512) {
                int4 v = d4[e];
                atomicAdd(&h[v.x >> 8], 1);
                atomicAdd(&h[v.y >> 8], 1);
                atomicAdd(&h[v.z >> 8], 1);
                atomicAdd(&h[v.w >> 8], 1);
            }
            __syncthreads();
            if (t < NBUCK) bcnt[t * NBLK1 + b] = h[t];
            __syncthreads();
        } else {
            for (int idx = t; idx < 64 * 64; idx += 512) {
                int k = idx >> 6, col = idx & 63;
                Wt2[col * 64 + (k ^ ((col & 7) << 3))] = __float2half(W2[idx]);
            }
        }
    }
    grid.sync();

    // ---- P2: scan of bcnt (49 chunks x 512) ----
    for (int c = blockIdx.x; c < NPART; c += gridDim.x) {
        int* tmp = (int*)lds;
        int i = c * 512 + t;
        int v = bcnt[i];
        tmp[t] = v;
        __syncthreads();
        for (int off = 1; off < 512; off <<= 1) {
            int u = (t >= off) ? tmp[t - off] : 0;
            __syncthreads();
            tmp[t] += u;
            __syncthreads();
        }
        boffs[i] = tmp[t] - v;
        if (t == 511) part[c] = tmp[t];
        __syncthreads();
    }
    grid.sync();

    // ---- P3: bucket scatter ----
    for (int b = blockIdx.x; b < NBLK1; b += gridDim.x) {
        int* cur = (int*)lds;
        int* sp  = (int*)(lds + 1024);
        scan_partials49(part, sp);
        if (t < NBUCK) {
            int idx = t * NBLK1 + b;
            cur[t] = boffs[idx] + sp[idx >> 9];
        }
        __syncthreads();
        int beg = b * EPB, end = min(beg + EPB, NEDGES);
        for (int e = beg + t; e < end; e += 512) {
            int d = dst[e];
            int pos = atomicAdd(&cur[d >> 8], 1);
            ep[pos] = (src[e] << 8) | (d & 255);
        }
        __syncthreads();
    }
    grid.sync();

    // ---- P4: per-bucket fine CSR (LDS counting sort) ----
    for (int buck = blockIdx.x; buck < NBUCK; buck += gridDim.x) {
        int* h   = (int*)lds;
        int* cur = (int*)(lds + 1024);
        int* sp  = (int*)(lds + 2048);
        int* stg = (int*)(lds + 4096);
        int* srt = (int*)(lds + 20480);
        scan_partials49(part, sp);
        int bi = buck * NBLK1;
        int base = boffs[bi] + sp[bi >> 9];
        int endp;
        if (buck == NBUCK - 1) endp = NEDGES;
        else {
            int e2 = (buck + 1) * NBLK1;
            endp = boffs[e2] + sp[e2 >> 9];
        }
        int cnt = endp - base;
        bool fits = (cnt <= FCAP);

        if (t < NBUCK) h[t] = 0;
        __syncthreads();
        if (fits) {
            for (int j = t; j < cnt; j += 512) stg[j] = ep[base + j];
            __syncthreads();
            for (int j = t; j < cnt; j += 512) atomicAdd(&h[stg[j] & 255], 1);
        } else {
            for (int i = base + t; i < endp; i += 512) atomicAdd(&h[ep[i] & 255], 1);
        }
        __syncthreads();
        int v = (t < NBUCK) ? h[t] : 0;
        for (int off = 1; off < 256; off <<= 1) {
            int u = (t >= off && t < NBUCK) ? h[t - off] : 0;
            __syncthreads();
            if (t < NBUCK) h[t] += u;
            __syncthreads();
        }
        if (t < NBUCK) {
            int excl = h[t] - v;
            int node = buck * 256 + t;
            if (node <= NNODES) offs[node] = base + excl;
            cur[t] = excl;
        }
        __syncthreads();
        if (fits) {
            for (int j = t; j < cnt; j += 512) {
                int p = stg[j];
                int pos = atomicAdd(&cur[p & 255], 1);
                srt[pos] = p >> 8;
            }
            __syncthreads();
            for (int j = t; j < cnt; j += 512) esrc[base + j] = srt[j];
        } else {
            for (int i = base + t; i < endp; i += 512) {
                int p = ep[i];
                int pos = atomicAdd(&cur[p & 255], 1);
                esrc[base + pos] = p >> 8;
            }
        }
        __syncthreads();
    }
    grid.sync();

    // ---- P5: aggregation layer 1 (relu, fp16 out) ----
    {
        int wid = t >> 6, lane = t & 63;
        int2* smw = ((int2*)lds) + wid * 64;
        for (int p = blockIdx.x * 8 + wid; p < NPAIR; p += gridDim.x * 8)
            agg_pair<1, 0, 1>(p, lane, smw, esrc, offs, H, AS, AD, b1, OUT1);
    }
    grid.sync();

    // ---- P6: gemm layer 2 ----
    for (int it = blockIdx.x; it < NGEMM1; it += gridDim.x)
        gemm_tile<64, 1, 1>(lds, it, OUT1, Wt2, as2, ad2, H, AS, AD);
    grid.sync();

    // ---- P7: aggregation layer 2 (l2-normalize, fp32 out) ----
    {
        int wid = t >> 6, lane = t & 63;
        int2* smw = ((int2*)lds) + wid * 64;
        for (int p = blockIdx.x * 8 + wid; p < NPAIR; p += gridDim.x * 8)
            agg_pair<0, 1, 0>(p, lane, smw, esrc, offs, H, AS, AD, b2, outF);
    }
}

// ---------------- launch ----------------

extern "C" void kernel_launch(void* const* d_in, const int* in_sizes, int n_in,
                              void* d_out, int out_size, void* d_ws, size_t ws_size,
                              hipStream_t stream) {
    const float* x   = (const float*)d_in[0];
    const int*   ei  = (const int*)d_in[1];
    const float* W1  = (const float*)d_in[2];
    const float* as1 = (const float*)d_in[3];
    const float* ad1 = (const float*)d_in[4];
    const float* b1  = (const float*)d_in[5];
    const float* W2  = (const float*)d_in[6];
    const float* as2 = (const float*)d_in[7];
    const float* ad2 = (const float*)d_in[8];
    const float* b2  = (const float*)d_in[9];
    float* outF = (float*)d_out;

    char* ws = (char*)d_ws;
    size_t off = 0;
    auto alloc = [&](size_t bytes) -> void* {
        void* p = ws + off;
        off = (off + bytes + 255) & ~(size_t)255;
        return p;
    };
    __half* H    = (__half*)alloc((size_t)NNODES * 64 * 2);
    __half* OUT1 = (__half*)alloc((size_t)NNODES * 64 * 2);
    float* AS    = (float*)alloc((size_t)NNODES * 4);
    float* AD    = (float*)alloc((size_t)NNODES * 4);
    int*   offs  = (int*)alloc((size_t)(NNODES + 1) * 4);
    int*   ep    = (int*)alloc((size_t)NEDGES * 4);
    int*   esrc  = (int*)alloc((size_t)NEDGES * 4);
    int*   bcnt  = (int*)alloc((size_t)SCANL * 4);
    int*   boffs = (int*)alloc((size_t)SCANL * 4);
    int*   part  = (int*)alloc((size_t)NPART * 4);
    __half* Wt2  = (__half*)alloc((size_t)64 * 64 * 2);

    int occ = 0;
    hipError_t e = hipOccupancyMaxActiveBlocksPerMultiprocessor(&occ, k_mega, 512, 0);
    if (e != hipSuccess || occ < 1) occ = 1;
    int grid = occ * 256;               // 256 CUs on MI355X
    if (grid > 1024) grid = 1024;

    void* args[] = {
        (void*)&x, (void*)&ei, (void*)&W1, (void*)&as1, (void*)&ad1, (void*)&b1,
        (void*)&W2, (void*)&as2, (void*)&ad2, (void*)&b2, (void*)&outF,
        (void*)&H, (void*)&OUT1, (void*)&AS, (void*)&AD,
        (void*)&offs, (void*)&ep, (void*)&esrc,
        (void*)&bcnt, (void*)&boffs, (void*)&part, (void*)&Wt2
    };
    hipLaunchCooperativeKernel((void*)k_mega, dim3(grid), dim3(512), args, 0, stream);
}

// Round 14
// 105.260 us; speedup vs baseline: 4.5951x; 4.5951x over previous
//
#include <hip/hip_runtime.h>
#include <hip/hip_fp16.h>
#include <math.h>

#define NNODES 50000
#define NEDGES 800000
#define NBUCK 256
#define EPB 8192
#define NBLK1 ((NEDGES + EPB - 1) / EPB)      // 98
#define SCANL (NBUCK * NBLK1)                  // 25088
#define SCANB ((SCANL + 1023) / 1024)          // 25
#define FCAP 8192                              // per-bucket LDS sort capacity
#define NGEMM1 ((NNODES + 63) / 64)            // 782

typedef _Float16 f16;
typedef _Float16 f16x4 __attribute__((ext_vector_type(4)));
typedef _Float16 f16x8 __attribute__((ext_vector_type(8)));
typedef float    f32x4 __attribute__((ext_vector_type(4)));

// ---------------- CSR build: two-level bucket sort, LDS atomics only ----------------
// Edge record packed into int32: (src << 8) | (dst & 255).  src < 2^17, fits.
// Blocks [NBLK1, NBLK1+2) double as W-prep: W^T -> fp16, swizzle baked in.

__global__ __launch_bounds__(256) void k_bcount(const int* __restrict__ dst,
                                                int* __restrict__ bcnt,
                                                const float* __restrict__ W1,
                                                const float* __restrict__ W2,
                                                __half* __restrict__ Wt1,
                                                __half* __restrict__ Wt2) {
    __shared__ int h[NBUCK];
    int t = threadIdx.x, b = blockIdx.x;
    if (b >= NBLK1) {
        if (b == NBLK1) {
            for (int idx = t; idx < 128 * 64; idx += 256) {
                int k = idx >> 6, col = idx & 63;
                Wt1[col * 128 + (k ^ ((col & 7) << 3))] = __float2half(W1[idx]);
            }
        } else {
            for (int idx = t; idx < 64 * 64; idx += 256) {
                int k = idx >> 6, col = idx & 63;
                Wt2[col * 64 + (k ^ ((col & 7) << 3))] = __float2half(W2[idx]);
            }
        }
        return;
    }
    h[t] = 0;
    __syncthreads();
    const int4* d4 = (const int4*)dst;
    int beg = b * (EPB / 4), end = min(beg + EPB / 4, NEDGES / 4);
    for (int e = beg + t; e < end; e += 256) {
        int4 v = d4[e];
        atomicAdd(&h[v.x >> 8], 1);
        atomicAdd(&h[v.y >> 8], 1);
        atomicAdd(&h[v.z >> 8], 1);
        atomicAdd(&h[v.w >> 8], 1);
    }
    __syncthreads();
    bcnt[t * NBLK1 + b] = h[t];
}

__global__ void k_scan_block(const int* __restrict__ in, int* __restrict__ out,
                             int* __restrict__ partial, int n) {
    __shared__ int tmp[1024];
    int t = threadIdx.x;
    int i = blockIdx.x * 1024 + t;
    int v = (i < n) ? in[i] : 0;
    tmp[t] = v;
    __syncthreads();
    for (int off = 1; off < 1024; off <<= 1) {
        int u = (t >= off) ? tmp[t - off] : 0;
        __syncthreads();
        tmp[t] += u;
        __syncthreads();
    }
    if (i < n) out[i] = tmp[t] - v;
    if (t == 1023) partial[blockIdx.x] = tmp[t];
}

__device__ __forceinline__ void scan_partials(const int* __restrict__ partial, int* sp) {
    int t = threadIdx.x;
    if (t < 64) {
        int v = (t < SCANB) ? partial[t] : 0;
        int incl = v;
        #pragma unroll
        for (int off = 1; off < 64; off <<= 1) {
            int u = __shfl_up(incl, off, 64);
            if (t >= off) incl += u;
        }
        if (t < SCANB) sp[t] = incl - v;
    }
    __syncthreads();
}

// ---------------- MFMA GEMM body (16x16x32 f16, fp32 accum) ----------------
// Xs [64][K] fp16 XOR-swizzled ((row&7)<<4 byte); Ws = W^T [64][K] same swizzle.
// A-frag: row=lane&15, k=(lane>>4)*8+j.  B-frag: col=lane&15, same k.
// C/D: col=lane&15, row=(lane>>4)*4+reg.

template<int K, int XH>
__device__ __forceinline__ void gemm_body(
    __half* __restrict__ Xs_h, __half* __restrict__ Ws_h, int bid,
    const void* __restrict__ Xv, const __half* __restrict__ WtSwz,
    const float* __restrict__ a_src, const float* __restrict__ a_dst,
    __half* __restrict__ H, float* __restrict__ AS, float* __restrict__ AD, int N)
{
    constexpr int KF = K / 4;
    constexpr int KFS = (K == 128) ? 5 : 4;
    int t = threadIdx.x;
    int n0 = bid * 64;

    {
        const uint2* wsrc = (const uint2*)WtSwz;
        uint2* wdst = (uint2*)Ws_h;
        #pragma unroll
        for (int f = t; f < K * 16; f += 256) wdst[f] = wsrc[f];
    }
    #pragma unroll
    for (int f = t; f < 64 * KF; f += 256) {
        int r = f >> KFS, k4 = f & (KF - 1);
        f16x4 hv = {0, 0, 0, 0};
        if (n0 + r < N) {
            if (XH) {
                union { uint2 u; f16x4 h4; } c;
                c.u = ((const uint2*)Xv)[(size_t)(n0 + r) * KF + k4];
                hv = c.h4;
            } else {
                float4 v = ((const float4*)Xv)[(size_t)(n0 + r) * KF + k4];
                hv[0] = (f16)v.x; hv[1] = (f16)v.y; hv[2] = (f16)v.z; hv[3] = (f16)v.w;
            }
        }
        int bo = (k4 * 8) ^ ((r & 7) << 4);
        *(f16x4*)((char*)Xs_h + r * (K * 2) + bo) = hv;
    }
    __syncthreads();

    int w = t >> 6, l = t & 63;
    int lg = l >> 4, l15 = l & 15;
    int rA = w * 16 + l15;
    int sw = (l15 & 7) << 4;

    f32x4 acc[4];
    #pragma unroll
    for (int ct = 0; ct < 4; ++ct) acc[ct] = (f32x4){0.f, 0.f, 0.f, 0.f};

    const char* pA = (const char*)Xs_h + rA * (K * 2);
    #pragma unroll
    for (int ks = 0; ks < K / 32; ++ks) {
        int ko = ks * 64 + (lg << 4);
        f16x8 a = *(const f16x8*)(pA + (ko ^ sw));
        #pragma unroll
        for (int ct = 0; ct < 4; ++ct) {
            const char* pB = (const char*)Ws_h + (ct * 16 + l15) * (K * 2) + (ko ^ sw);
            f16x8 bfr = *(const f16x8*)pB;
            acc[ct] = __builtin_amdgcn_mfma_f32_16x16x32_f16(a, bfr, acc[ct], 0, 0, 0);
        }
    }

    float asv[4], adv[4];
    #pragma unroll
    for (int ct = 0; ct < 4; ++ct) {
        asv[ct] = a_src[ct * 16 + l15];
        adv[ct] = a_dst[ct * 16 + l15];
    }
    #pragma unroll
    for (int reg = 0; reg < 4; ++reg) {
        int row = n0 + w * 16 + lg * 4 + reg;
        if (row < N) {
            float s1 = 0.f, s2 = 0.f;
            #pragma unroll
            for (int ct = 0; ct < 4; ++ct) {
                s1 = fmaf(acc[ct][reg], asv[ct], s1);
                s2 = fmaf(acc[ct][reg], adv[ct], s2);
            }
            #pragma unroll
            for (int o = 1; o < 16; o <<= 1) {
                s1 += __shfl_xor(s1, o, 64);
                s2 += __shfl_xor(s2, o, 64);
            }
            #pragma unroll
            for (int ct = 0; ct < 4; ++ct)
                H[(size_t)row * 64 + ct * 16 + l15] = __float2half(acc[ct][reg]);
            if (l15 == 0) { AS[row] = s1; AD[row] = s2; }
        }
    }
}

template<int K, int XH>
__global__ __launch_bounds__(256, 4) void k_gemm_att(
    const void* __restrict__ Xv, const __half* __restrict__ WtSwz,
    const float* __restrict__ a_src, const float* __restrict__ a_dst,
    __half* __restrict__ H, float* __restrict__ AS, float* __restrict__ AD, int N)
{
    __shared__ __align__(16) __half Xs[64 * K];
    __shared__ __align__(16) __half Ws[64 * K];
    gemm_body<K, XH>(Xs, Ws, blockIdx.x, Xv, WtSwz, a_src, a_dst, H, AS, AD, N);
}

// ---------------- fat kernel: gemm1 blocks [0,NGEMM1) || bscatter after ----------------

__global__ __launch_bounds__(256, 4) void k_gemm1_bscatter(
    const float* __restrict__ X, const __half* __restrict__ Wt1,
    const float* __restrict__ as1, const float* __restrict__ ad1,
    __half* __restrict__ H, float* __restrict__ AS, float* __restrict__ AD,
    const int* __restrict__ src, const int* __restrict__ dst,
    const int* __restrict__ boffs, const int* __restrict__ partial,
    int* __restrict__ ep)
{
    __shared__ __align__(16) __half Xs[64 * 128];
    __shared__ __align__(16) __half Ws[64 * 128];
    if (blockIdx.x < NGEMM1) {
        gemm_body<128, 0>(Xs, Ws, blockIdx.x, X, Wt1, as1, ad1, H, AS, AD, NNODES);
        return;
    }
    int* cur = (int*)Xs;
    int* sp  = (int*)Ws;
    int t = threadIdx.x, b = blockIdx.x - NGEMM1;
    scan_partials(partial, sp);
    int idx = t * NBLK1 + b;
    cur[t] = boffs[idx] + sp[idx >> 10];
    __syncthreads();
    int beg = b * EPB, end = min(beg + EPB, NEDGES);
    for (int e = beg + t; e < end; e += 256) {
        int d = dst[e];
        int pos = atomicAdd(&cur[d >> 8], 1);
        ep[pos] = (src[e] << 8) | (d & 255);
    }
}

// per-bucket fine CSR via in-LDS counting sort; coalesced esrc writes
__global__ __launch_bounds__(512) void k_fine(const int* __restrict__ ep,
                                              const int* __restrict__ boffs,
                                              const int* __restrict__ partial,
                                              int* __restrict__ offs,
                                              int* __restrict__ esrc) {
    __shared__ int h[NBUCK];
    __shared__ int cur[NBUCK];
    __shared__ int sp[SCANB];
    __shared__ int stg[FCAP];
    __shared__ int srt[FCAP];
    int t = threadIdx.x, buck = blockIdx.x;
    scan_partials(partial, sp);
    int bi = buck * NBLK1;
    int base = boffs[bi] + sp[bi >> 10];
    int endp;
    if (buck == NBUCK - 1) endp = NEDGES;
    else {
        int ei2 = (buck + 1) * NBLK1;
        endp = boffs[ei2] + sp[ei2 >> 10];
    }
    int cnt = endp - base;
    bool fits = (cnt <= FCAP);

    if (t < NBUCK) h[t] = 0;
    __syncthreads();
    if (fits) {
        for (int j = t; j < cnt; j += 512) stg[j] = ep[base + j];
        __syncthreads();
        for (int j = t; j < cnt; j += 512) atomicAdd(&h[stg[j] & 255], 1);
    } else {
        for (int i = base + t; i < endp; i += 512) atomicAdd(&h[ep[i] & 255], 1);
    }
    __syncthreads();
    int v = (t < NBUCK) ? h[t] : 0;
    for (int off = 1; off < 256; off <<= 1) {
        int u = (t >= off && t < NBUCK) ? h[t - off] : 0;
        __syncthreads();
        if (t < NBUCK) h[t] += u;
        __syncthreads();
    }
    if (t < NBUCK) {
        int excl = h[t] - v;
        int node = buck * 256 + t;
        if (node <= NNODES) offs[node] = base + excl;
        cur[t] = excl;
    }
    __syncthreads();
    if (fits) {
        for (int j = t; j < cnt; j += 512) {
            int p = stg[j];
            int pos = atomicAdd(&cur[p & 255], 1);
            srt[pos] = p >> 8;
        }
        __syncthreads();
        for (int j = t; j < cnt; j += 512) esrc[base + j] = srt[j];
    } else {
        for (int i = base + t; i < endp; i += 512) {
            int p = ep[i];
            int pos = atomicAdd(&cur[p & 255], 1);
            esrc[base + pos] = p >> 8;
        }
    }
}

// ---------------- per-dst aggregation: 2 nodes per wave ----------------
template<int RELU, int NORM, int OUTH>
__global__ __launch_bounds__(256) void k_agg(
    const int* __restrict__ esrc, const int* __restrict__ offs,
    const __half* __restrict__ H, const float* __restrict__ AS,
    const float* __restrict__ AD, const float* __restrict__ bias,
    void* __restrict__ outv, int N)
{
    __shared__ int2 sm[4][64];
    int gid = blockIdx.x * blockDim.x + threadIdx.x;
    int w = gid >> 6;
    int lane = gid & 63;
    int wid = threadIdx.x >> 6;
    int n0 = 2 * w;
    if (n0 >= N) return;
    int half = lane >> 5, fp = lane & 31;
    int nh = n0 + half;
    bool valid = nh < N;
    int beg = valid ? offs[nh] : 0;
    int end = valid ? offs[nh + 1] : 0;
    int deg = end - beg;
    int degO = __shfl_xor(deg, 32, 64);
    int dm = max(deg, degO);
    float2 bp = ((const float2*)bias)[fp];

    if (dm <= 32) {
        float add = valid ? AD[nh] : 0.f;
        int s = 0;
        float logit = -3.0e38f;
        if (fp < deg) {
            s = esrc[beg + fp];
            float l0 = AS[s] + add;
            logit = (l0 > 0.f) ? l0 : 0.2f * l0;
        }
        float m = logit;
        #pragma unroll
        for (int o = 16; o > 0; o >>= 1) m = fmaxf(m, __shfl_xor(m, o, 64));
        float wg = (fp < deg) ? __expf(logit - m) : 0.f;
        float z = wg;
        #pragma unroll
        for (int o = 16; o > 0; o >>= 1) z += __shfl_xor(z, o, 64);
        sm[wid][lane] = make_int2(s, __float_as_int(wg));

        const __half2* H2 = (const __half2*)H;
        float2 a0 = {0.f, 0.f}, a1 = {0.f, 0.f};
        int base = half * 32;
        int k = 0;
        for (; k + 1 < dm; k += 2) {
            int4 v = *(const int4*)&sm[wid][base + k];
            float2 h0 = __half22float2(H2[(size_t)v.x * 32 + fp]);
            float2 h1 = __half22float2(H2[(size_t)v.z * 32 + fp]);
            float w0 = __int_as_float(v.y), w1 = __int_as_float(v.w);
            a0.x = fmaf(w0, h0.x, a0.x); a0.y = fmaf(w0, h0.y, a0.y);
            a1.x = fmaf(w1, h1.x, a1.x); a1.y = fmaf(w1, h1.y, a1.y);
        }
        if (k < dm) {
            int2 v = sm[wid][base + k];
            float2 h0 = __half22float2(H2[(size_t)v.x * 32 + fp]);
            float w0 = __int_as_float(v.y);
            a0.x = fmaf(w0, h0.x, a0.x); a0.y = fmaf(w0, h0.y, a0.y);
        }
        float2 acc = {a0.x + a1.x, a0.y + a1.y};
        float rz = (deg > 0) ? (1.0f / z) : 0.f;
        float2 val2 = make_float2(fmaf(acc.x, rz, bp.x), fmaf(acc.y, rz, bp.y));
        if (RELU) { val2.x = fmaxf(val2.x, 0.f); val2.y = fmaxf(val2.y, 0.f); }
        if (NORM) {
            float ss = val2.x * val2.x + val2.y * val2.y;
            #pragma unroll
            for (int o = 16; o > 0; o >>= 1) ss += __shfl_xor(ss, o, 64);
            float inv = 1.0f / fmaxf(sqrtf(ss), 1e-12f);
            val2.x *= inv; val2.y *= inv;
        }
        if (valid) {
            if (OUTH) ((__half2*)outv)[(size_t)nh * 32 + fp] = __floats2half2_rn(val2.x, val2.y);
            else      ((float2*)outv)[(size_t)nh * 32 + fp] = val2;
        }
        return;
    }

    // ---- rare fallback: per node with the full wave ----
    #pragma unroll 1
    for (int side = 0; side < 2; ++side) {
        int n = n0 + side;
        if (n >= N) break;
        int b2 = offs[n], e2 = offs[n + 1];
        int dg = e2 - b2;
        float add = AD[n];
        if (dg <= 64) {
            int s = 0;
            float logit = -3.0e38f;
            if (lane < dg) {
                s = esrc[b2 + lane];
                float l0 = AS[s] + add;
                logit = (l0 > 0.f) ? l0 : 0.2f * l0;
            }
            float m = logit;
            #pragma unroll
            for (int o = 32; o > 0; o >>= 1) m = fmaxf(m, __shfl_xor(m, o, 64));
            float wg = (lane < dg) ? __expf(logit - m) : 0.f;
            float z = wg;
            #pragma unroll
            for (int o = 32; o > 0; o >>= 1) z += __shfl_xor(z, o, 64);
            sm[wid][lane] = make_int2(s, __float_as_int(wg));
            const __half2* H2 = (const __half2*)H;
            float2 a0 = {0.f, 0.f};
            for (int k = half; k < dg; k += 2) {
                int2 v = sm[wid][k];
                float2 h0 = __half22float2(H2[(size_t)v.x * 32 + fp]);
                float w0 = __int_as_float(v.y);
                a0.x = fmaf(w0, h0.x, a0.x); a0.y = fmaf(w0, h0.y, a0.y);
            }
            a0.x += __shfl_xor(a0.x, 32, 64);
            a0.y += __shfl_xor(a0.y, 32, 64);
            float rz = (dg > 0) ? (1.0f / z) : 0.f;
            float2 val2 = make_float2(fmaf(a0.x, rz, bp.x), fmaf(a0.y, rz, bp.y));
            if (RELU) { val2.x = fmaxf(val2.x, 0.f); val2.y = fmaxf(val2.y, 0.f); }
            if (NORM) {
                float ss = val2.x * val2.x + val2.y * val2.y;
                #pragma unroll
                for (int o = 16; o > 0; o >>= 1) ss += __shfl_xor(ss, o, 64);
                float inv = 1.0f / fmaxf(sqrtf(ss), 1e-12f);
                val2.x *= inv; val2.y *= inv;
            }
            if (half == 0) {
                if (OUTH) ((__half2*)outv)[(size_t)n * 32 + fp] = __floats2half2_rn(val2.x, val2.y);
                else      ((float2*)outv)[(size_t)n * 32 + fp] = val2;
            }
        } else {
            float m = -3.0e38f, z = 0.f, acc = 0.f;
            for (int i = b2; i < e2; ++i) {
                int s = esrc[i];
                float l0 = AS[s] + add;
                l0 = (l0 > 0.f) ? l0 : 0.2f * l0;
                float mn = fmaxf(m, l0);
                float sc = __expf(m - mn);
                float wgt = __expf(l0 - mn);
                z = z * sc + wgt;
                acc = acc * sc + wgt * __half2float(H[(size_t)s * 64 + lane]);
                m = mn;
            }
            float val = acc / z + bias[lane];
            if (RELU) val = fmaxf(val, 0.f);
            if (NORM) {
                float ss = val * val;
                #pragma unroll
                for (int o = 32; o > 0; o >>= 1) ss += __shfl_xor(ss, o, 64);
                val = val / fmaxf(sqrtf(ss), 1e-12f);
            }
            if (OUTH) ((__half*)outv)[(size_t)n * 64 + lane] = __float2half(val);
            else      ((float*)outv)[(size_t)n * 64 + lane] = val;
        }
    }
}

// ---------------- launch ----------------

extern "C" void kernel_launch(void* const* d_in, const int* in_sizes, int n_in,
                              void* d_out, int out_size, void* d_ws, size_t ws_size,
                              hipStream_t stream) {
    const float* x   = (const float*)d_in[0];
    const int*   ei  = (const int*)d_in[1];
    const float* W1  = (const float*)d_in[2];
    const float* as1 = (const float*)d_in[3];
    const float* ad1 = (const float*)d_in[4];
    const float* b1  = (const float*)d_in[5];
    const float* W2  = (const float*)d_in[6];
    const float* as2 = (const float*)d_in[7];
    const float* ad2 = (const float*)d_in[8];
    const float* b2  = (const float*)d_in[9];
    const int* src = ei;
    const int* dst = ei + NEDGES;

    char* ws = (char*)d_ws;
    size_t off = 0;
    auto alloc = [&](size_t bytes) -> void* {
        void* p = ws + off;
        off = (off + bytes + 255) & ~(size_t)255;
        return p;
    };
    __half* H    = (__half*)alloc((size_t)NNODES * 64 * 2);
    __half* OUT1 = (__half*)alloc((size_t)NNODES * 64 * 2);
    float* AS    = (float*)alloc((size_t)NNODES * 4);
    float* AD    = (float*)alloc((size_t)NNODES * 4);
    int*   offs  = (int*)alloc((size_t)(NNODES + 1) * 4);
    int*   ep    = (int*)alloc((size_t)NEDGES * 4);
    int*   esrc  = (int*)alloc((size_t)NEDGES * 4);
    int*   bcnt  = (int*)alloc((size_t)SCANL * 4);
    int*   boffs = (int*)alloc((size_t)SCANL * 4);
    int*   part1 = (int*)alloc((size_t)SCANB * 4);
    __half* Wt1  = (__half*)alloc((size_t)64 * 128 * 2);
    __half* Wt2  = (__half*)alloc((size_t)64 * 64 * 2);

    // CSR build + W prep (fused roles) — no global atomics
    k_bcount<<<NBLK1 + 2, 256, 0, stream>>>(dst, bcnt, W1, W2, Wt1, Wt2);
    k_scan_block<<<SCANB, 1024, 0, stream>>>(bcnt, boffs, part1, SCANL);
    // fused: MFMA gemm1 (blocks [0,782)) concurrent with bscatter
    k_gemm1_bscatter<<<NGEMM1 + NBLK1, 256, 0, stream>>>(
        x, Wt1, as1, ad1, H, AS, AD, src, dst, boffs, part1, ep);
    k_fine<<<NBUCK, 512, 0, stream>>>(ep, boffs, part1, offs, esrc);

    int aggBlocks = (NNODES / 2 + 3) / 4;  // 2 nodes/wave, 4 waves/block
    // Layer 1 aggregation
    k_agg<1, 0, 1><<<aggBlocks, 256, 0, stream>>>(esrc, offs, H, AS, AD, b1, OUT1, NNODES);

    // Layer 2
    k_gemm_att<64, 1><<<(NNODES + 63) / 64, 256, 0, stream>>>(OUT1, Wt2, as2, ad2, H, AS, AD, NNODES);
    k_agg<0, 1, 0><<<aggBlocks, 256, 0, stream>>>(esrc, offs, H, AS, AD, b2, d_out, NNODES);
}